// Round 6
// baseline (5874.085 us; speedup 1.0000x reference)
//
#include <hip/hip_runtime.h>
#include <hip/hip_bf16.h>

#define BB 8
#define LL 2048
#define DM 512
#define DI 1024
#define DS 16
#define DTR 32
#define DFF 2048
#define BL (BB * LL)

typedef __hip_bfloat16 bf16;
struct bf4 { bf16 x, y, z, w; };

__device__ __forceinline__ float silu_f(float x) { return x / (1.f + __expf(-x)); }
__device__ __forceinline__ float softplus_f(float x) { return x > 20.f ? x : log1pf(__expf(x)); }
__device__ __forceinline__ float gelu_f(float x) { return 0.5f * x * (1.f + erff(x * 0.70710678118654752f)); }
__device__ __forceinline__ float b2f(bf16 v) { return __bfloat162float(v); }

__device__ __forceinline__ float4 ld4(const float* p) { return *(const float4*)p; }
__device__ __forceinline__ float4 ld4(const bf16* p) {
    bf4 v = *(const bf4*)p;
    return make_float4(b2f(v.x), b2f(v.y), b2f(v.z), b2f(v.w));
}
__device__ __forceinline__ bf4 pack4(float a, float b, float c, float d) {
    bf4 o; o.x = __float2bfloat16(a); o.y = __float2bfloat16(b);
    o.z = __float2bfloat16(c); o.w = __float2bfloat16(d); return o;
}

// ---------------- GEMM: C[m,n] = sum_k A[m,k] * W[n,k] (+ epilogue) ----------------
enum { EP_BF16, EP_SOFTPLUS, EP_GELU, EP_F32, EP_RESF, EP_ACC, EP_BIASRES };

template <int EPI, typename TA>
__global__ __launch_bounds__(256) void gemm_nt(
    const TA* __restrict__ A, int lda,
    const float* __restrict__ W, int ldb,
    void* __restrict__ Cv, int ldc,
    int K,
    const float* __restrict__ bias,
    const void* __restrict__ resv)
{
    __shared__ float As[16][64];
    __shared__ float Bs[16][64];
    const int tid = threadIdx.x;
    const int tx = tid & 15, ty = tid >> 4;
    const int m0 = blockIdx.y * 64, n0 = blockIdx.x * 64;
    const int lrow = tid >> 2;
    const int lcol = (tid & 3) << 2;

    const TA* Ap = A + (size_t)(m0 + lrow) * lda + lcol;
    const float* Bp = W + (size_t)(n0 + lrow) * ldb + lcol;

    float acc[4][4] = {};

    for (int k0 = 0; k0 < K; k0 += 16) {
        float4 av = ld4(Ap + k0);
        float4 bv = ld4(Bp + k0);
        __syncthreads();
        As[lcol + 0][lrow] = av.x; As[lcol + 1][lrow] = av.y;
        As[lcol + 2][lrow] = av.z; As[lcol + 3][lrow] = av.w;
        Bs[lcol + 0][lrow] = bv.x; Bs[lcol + 1][lrow] = bv.y;
        Bs[lcol + 2][lrow] = bv.z; Bs[lcol + 3][lrow] = bv.w;
        __syncthreads();
#pragma unroll
        for (int kk = 0; kk < 16; ++kk) {
            float4 a4 = *(const float4*)(&As[kk][ty << 2]);
            float4 b4 = *(const float4*)(&Bs[kk][tx << 2]);
            float aa[4] = {a4.x, a4.y, a4.z, a4.w};
            float bb[4] = {b4.x, b4.y, b4.z, b4.w};
#pragma unroll
            for (int i = 0; i < 4; ++i)
#pragma unroll
                for (int j = 0; j < 4; ++j)
                    acc[i][j] = fmaf(aa[i], bb[j], acc[i][j]);
        }
    }

#pragma unroll
    for (int i = 0; i < 4; ++i) {
        const int m = m0 + (ty << 2) + i;
        const int n = n0 + (tx << 2);
        float v[4] = {acc[i][0], acc[i][1], acc[i][2], acc[i][3]};
        const size_t co = (size_t)m * ldc + n;
        if constexpr (EPI == EP_BF16) {
            *(bf4*)((bf16*)Cv + co) = pack4(v[0], v[1], v[2], v[3]);
        } else if constexpr (EPI == EP_SOFTPLUS) {
            *(bf4*)((bf16*)Cv + co) = pack4(
                softplus_f(v[0] + bias[n + 0]), softplus_f(v[1] + bias[n + 1]),
                softplus_f(v[2] + bias[n + 2]), softplus_f(v[3] + bias[n + 3]));
        } else if constexpr (EPI == EP_GELU) {
            *(bf4*)((bf16*)Cv + co) = pack4(
                gelu_f(v[0] + bias[n + 0]), gelu_f(v[1] + bias[n + 1]),
                gelu_f(v[2] + bias[n + 2]), gelu_f(v[3] + bias[n + 3]));
        } else if constexpr (EPI == EP_F32) {
            float4 o = {v[0], v[1], v[2], v[3]};
            *(float4*)((float*)Cv + co) = o;
        } else if constexpr (EPI == EP_RESF) {
            float4 rv = *(const float4*)((const float*)resv + co);
            float4 o = {v[0] + rv.x, v[1] + rv.y, v[2] + rv.z, v[3] + rv.w};
            *(float4*)((float*)Cv + co) = o;
        } else if constexpr (EPI == EP_ACC) {
            float* cp = (float*)Cv + co;
            float4 old = *(const float4*)cp;
            float4 o = {v[0] + old.x, v[1] + old.y, v[2] + old.z, v[3] + old.w};
            *(float4*)cp = o;
        } else if constexpr (EPI == EP_BIASRES) {
            float4 rv = ld4((const bf16*)resv + co);
            float4 o = {v[0] + bias[n + 0] + rv.x, v[1] + bias[n + 1] + rv.y,
                        v[2] + bias[n + 2] + rv.z, v[3] + bias[n + 3] + rv.w};
            *(float4*)((float*)Cv + co) = o;
        }
    }
}

// ---------------- depthwise conv (D_CONV=2) + SiLU ----------------
__global__ __launch_bounds__(256) void conv_silu_kernel(
    const bf16* __restrict__ xz, const float* __restrict__ cw,
    const float* __restrict__ cb, bf16* __restrict__ xic, int nbr)
{
    const int idx = blockIdx.x * 256 + threadIdx.x;
    const int c4 = (idx & 255) << 2;
    const int row = idx >> 8;
    const int l = row & (LL - 1);
    const int lnbr = l + nbr;
    const bool valid = (lnbr >= 0) && (lnbr < LL);

    const bf16* pc = xz + (size_t)row * (2 * DI) + c4;
    float4 cur = ld4(pc);
    float4 prv = make_float4(0.f, 0.f, 0.f, 0.f);
    if (valid) prv = ld4(pc + (ptrdiff_t)nbr * (2 * DI));

    float w0[4], w1[4];
#pragma unroll
    for (int q = 0; q < 4; ++q) { w0[q] = cw[(c4 + q) * 2]; w1[q] = cw[(c4 + q) * 2 + 1]; }
    float4 bb = ld4(cb + c4);

    *(bf4*)(xic + (size_t)row * DI + c4) = pack4(
        silu_f(fmaf(w0[0], prv.x, fmaf(w1[0], cur.x, bb.x))),
        silu_f(fmaf(w0[1], prv.y, fmaf(w1[1], cur.y, bb.y))),
        silu_f(fmaf(w0[2], prv.z, fmaf(w1[2], cur.z, bb.z))),
        silu_f(fmaf(w0[3], prv.w, fmaf(w1[3], cur.w, bb.w))));
}

// ---------------- selective scan ----------------
__global__ __launch_bounds__(256) void scan_kernel(
    const bf16* __restrict__ xic, const bf16* __restrict__ xz,
    const float* __restrict__ xdb, bf16* __restrict__ dty,
    const float* __restrict__ A_log, const float* __restrict__ Dskip,
    int t0, int tstep)
{
    const int tid = threadIdx.x;
    const int s = tid & 15;
    const int dl = tid >> 4;
    const int blk = blockIdx.x;
    const int b = blk >> 6;
    const int d = ((blk & 63) << 4) + dl;

    const float a = -expf(A_log[d * DS + s]);
    const float dsk = Dskip[d];
    float h = 0.f;

    const size_t base = (size_t)(b * LL + t0);
    const bf16* pu = xic + base * DI + d;
    bf16* pdt = dty + base * DI + d;
    const bf16* pz = xz + base * (2 * DI) + DI + d;
    const float* pB = xdb + base * 64 + DTR + s;
    const ptrdiff_t s1 = (ptrdiff_t)tstep * DI;
    const ptrdiff_t s2 = (ptrdiff_t)tstep * (2 * DI);
    const ptrdiff_t s3 = (ptrdiff_t)tstep * 64;

#pragma unroll 2
    for (int it = 0; it < LL; ++it) {
        const float u = b2f(*pu);
        const float dtv = b2f(*pdt);
        const float Bv = *pB;
        const float Cv = *(pB + DS);
        const float zv = b2f(*pz);

        const float dA = __expf(dtv * a);
        h = fmaf(dA, h, dtv * u * Bv);
        float p = h * Cv;
        p += __shfl_xor(p, 1);
        p += __shfl_xor(p, 2);
        p += __shfl_xor(p, 4);
        p += __shfl_xor(p, 8);
        if (s == 0) {
            const float y = fmaf(u, dsk, p);
            *pdt = __float2bfloat16(y * silu_f(zv));
        }
        pu += s1; pdt += s1; pz += s2; pB += s3;
    }
}

// ---------------- layernorm (fp32 in; OUT: 0=bf16 ws, 1=fp32 d_out) ----------------
template <int OUTF>
__global__ __launch_bounds__(256) void ln_kernel(
    const float* __restrict__ in, const float* __restrict__ g,
    const float* __restrict__ bta, void* __restrict__ outv)
{
    const int row = blockIdx.x;
    const int t = threadIdx.x;
    const float* p = in + (size_t)row * DM;
    const float v0 = p[t];
    const float v1 = p[t + 256];
    float sm = v0 + v1;
    float sq = v0 * v0 + v1 * v1;
#pragma unroll
    for (int off = 32; off > 0; off >>= 1) {
        sm += __shfl_xor(sm, off);
        sq += __shfl_xor(sq, off);
    }
    __shared__ float red[8];
    const int w = t >> 6;
    if ((t & 63) == 0) { red[w] = sm; red[4 + w] = sq; }
    __syncthreads();
    sm = red[0] + red[1] + red[2] + red[3];
    sq = red[4] + red[5] + red[6] + red[7];
    const float mean = sm * (1.f / DM);
    const float var = sq * (1.f / DM) - mean * mean;
    const float rstd = rsqrtf(var + 1e-5f);
    const float o0 = (v0 - mean) * rstd * g[t] + bta[t];
    const float o1 = (v1 - mean) * rstd * g[t + 256] + bta[t + 256];
    if constexpr (OUTF == 0) {
        bf16* out = (bf16*)outv;
        out[(size_t)row * DM + t] = __float2bfloat16(o0);
        out[(size_t)row * DM + t + 256] = __float2bfloat16(o1);
    } else {
        float* out = (float*)outv;
        out[(size_t)row * DM + t] = o0;
        out[(size_t)row * DM + t + 256] = o1;
    }
}

// ---------------------------------------------------------------------------
extern "C" void kernel_launch(void* const* d_in, const int* in_sizes, int n_in,
                              void* d_out, int out_size, void* d_ws, size_t ws_size,
                              hipStream_t stream)
{
    const float* x = (const float*)d_in[0];
    const float* ffn_w1 = (const float*)d_in[19];
    const float* ffn_b1 = (const float*)d_in[20];
    const float* ffn_w2 = (const float*)d_in[21];
    const float* ffn_b2 = (const float*)d_in[22];
    const float* ln1_g = (const float*)d_in[23];
    const float* ln1_b = (const float*)d_in[24];
    const float* ln2_g = (const float*)d_in[25];
    const float* ln2_b = (const float*)d_in[26];

    char* p = (char*)d_ws;
    auto alloc = [&](size_t bytes) { void* r = (void*)p; p += (bytes + 255) & ~(size_t)255; return r; };
    bf16* xz   = (bf16*)alloc((size_t)BL * 2048 * 2);   // xz / FFN hidden (reused)
    bf16* xic  = (bf16*)alloc((size_t)BL * DI * 2);     // conv output u
    bf16* dtb  = (bf16*)alloc((size_t)BL * DI * 2);     // dt -> y (in place)
    float* xdb = (float*)alloc((size_t)BL * 64 * 4);    // x_dbl (fp32)
    float* sum = (float*)alloc((size_t)BL * DM * 4);    // residual accumulator (fp32)
    bf16* x1   = (bf16*)alloc((size_t)BL * DM * 2);     // LN1 output

    const dim3 blk(256);
    for (int dir = 0; dir < 2; ++dir) {
        const int o = 1 + dir * 9;
        const float* in_proj = (const float*)d_in[o + 0];
        const float* conv_w  = (const float*)d_in[o + 1];
        const float* conv_b  = (const float*)d_in[o + 2];
        const float* x_proj  = (const float*)d_in[o + 3];
        const float* dt_w    = (const float*)d_in[o + 4];
        const float* dt_b    = (const float*)d_in[o + 5];
        const float* A_log   = (const float*)d_in[o + 6];
        const float* Dskip   = (const float*)d_in[o + 7];
        const float* out_proj= (const float*)d_in[o + 8];

        const int nbr = (dir == 0) ? -1 : +1;
        const int t0 = (dir == 0) ? 0 : (LL - 1);
        const int tstep = (dir == 0) ? 1 : -1;

        gemm_nt<EP_BF16, float><<<dim3((2 * DI) / 64, BL / 64), blk, 0, stream>>>(
            x, DM, in_proj, DM, xz, 2 * DI, DM, nullptr, nullptr);
        conv_silu_kernel<<<BL, blk, 0, stream>>>(xz, conv_w, conv_b, xic, nbr);
        gemm_nt<EP_F32, bf16><<<dim3(1, BL / 64), blk, 0, stream>>>(
            xic, DI, x_proj, DI, xdb, 64, DI, nullptr, nullptr);
        gemm_nt<EP_SOFTPLUS, float><<<dim3(DI / 64, BL / 64), blk, 0, stream>>>(
            xdb, 64, dt_w, DTR, dtb, DI, DTR, dt_b, nullptr);
        scan_kernel<<<BB * (DI / 16), blk, 0, stream>>>(
            xic, xz, xdb, dtb, A_log, Dskip, t0, tstep);
        if (dir == 0)
            gemm_nt<EP_RESF, bf16><<<dim3(DM / 64, BL / 64), blk, 0, stream>>>(
                dtb, DI, out_proj, DI, sum, DM, DI, nullptr, x);
        else
            gemm_nt<EP_ACC, bf16><<<dim3(DM / 64, BL / 64), blk, 0, stream>>>(
                dtb, DI, out_proj, DI, sum, DM, DI, nullptr, nullptr);
    }

    // LN1 -> x1 (bf16)
    ln_kernel<0><<<BL, blk, 0, stream>>>(sum, ln1_g, ln1_b, x1);
    // h = gelu(x1 @ w1^T + b1) -> xz (bf16)
    gemm_nt<EP_GELU, bf16><<<dim3(DFF / 64, BL / 64), blk, 0, stream>>>(
        x1, DM, ffn_w1, DM, xz, DFF, DM, ffn_b1, nullptr);
    // sum = h @ w2^T + b2 + x1 (fp32)
    gemm_nt<EP_BIASRES, bf16><<<dim3(DM / 64, BL / 64), blk, 0, stream>>>(
        xz, DFF, ffn_w2, DFF, sum, DM, DFF, ffn_b2, x1);
    // LN2 -> fp32 output (d_out is float32!)
    ln_kernel<1><<<BL, blk, 0, stream>>>(sum, ln2_g, ln2_b, d_out);
}

// Round 7
// 3034.512 us; speedup vs baseline: 1.9358x; 1.9358x over previous
//
#include <hip/hip_runtime.h>
#include <hip/hip_bf16.h>

#define BB 8
#define LL 2048
#define DM 512
#define DI 1024
#define DS 16
#define DTR 32
#define DFF 2048
#define BL (BB * LL)
#define CH 32
#define NCH (LL / CH)   // 64

typedef __hip_bfloat16 bf16;
struct bf4 { bf16 x, y, z, w; };

__device__ __forceinline__ float silu_f(float x) { return x / (1.f + __expf(-x)); }
__device__ __forceinline__ float softplus_f(float x) { return x > 20.f ? x : log1pf(__expf(x)); }
__device__ __forceinline__ float gelu_f(float x) { return 0.5f * x * (1.f + erff(x * 0.70710678118654752f)); }
__device__ __forceinline__ float b2f(bf16 v) { return __bfloat162float(v); }

__device__ __forceinline__ float4 ld4(const float* p) { return *(const float4*)p; }
__device__ __forceinline__ float4 ld4(const bf16* p) {
    bf4 v = *(const bf4*)p;
    return make_float4(b2f(v.x), b2f(v.y), b2f(v.z), b2f(v.w));
}
__device__ __forceinline__ bf4 pack4(float a, float b, float c, float d) {
    bf4 o; o.x = __float2bfloat16(a); o.y = __float2bfloat16(b);
    o.z = __float2bfloat16(c); o.w = __float2bfloat16(d); return o;
}

// ---------------- GEMM: C[m,n] = sum_k A[m,k] * W[n,k] (+ epilogue) ----------------
enum { EP_BF16, EP_SOFTPLUS, EP_GELU, EP_F32, EP_RESF, EP_ACC, EP_BIASRES };

template <int EPI, typename TA>
__global__ __launch_bounds__(256) void gemm_nt(
    const TA* __restrict__ A, int lda,
    const float* __restrict__ W, int ldb,
    void* __restrict__ Cv, int ldc,
    int K,
    const float* __restrict__ bias,
    const void* __restrict__ resv)
{
    __shared__ float As[16][64];
    __shared__ float Bs[16][64];
    const int tid = threadIdx.x;
    const int tx = tid & 15, ty = tid >> 4;
    const int m0 = blockIdx.y * 64, n0 = blockIdx.x * 64;
    const int lrow = tid >> 2;
    const int lcol = (tid & 3) << 2;

    const TA* Ap = A + (size_t)(m0 + lrow) * lda + lcol;
    const float* Bp = W + (size_t)(n0 + lrow) * ldb + lcol;

    float acc[4][4] = {};

    for (int k0 = 0; k0 < K; k0 += 16) {
        float4 av = ld4(Ap + k0);
        float4 bv = ld4(Bp + k0);
        __syncthreads();
        As[lcol + 0][lrow] = av.x; As[lcol + 1][lrow] = av.y;
        As[lcol + 2][lrow] = av.z; As[lcol + 3][lrow] = av.w;
        Bs[lcol + 0][lrow] = bv.x; Bs[lcol + 1][lrow] = bv.y;
        Bs[lcol + 2][lrow] = bv.z; Bs[lcol + 3][lrow] = bv.w;
        __syncthreads();
#pragma unroll
        for (int kk = 0; kk < 16; ++kk) {
            float4 a4 = *(const float4*)(&As[kk][ty << 2]);
            float4 b4 = *(const float4*)(&Bs[kk][tx << 2]);
            float aa[4] = {a4.x, a4.y, a4.z, a4.w};
            float bb[4] = {b4.x, b4.y, b4.z, b4.w};
#pragma unroll
            for (int i = 0; i < 4; ++i)
#pragma unroll
                for (int j = 0; j < 4; ++j)
                    acc[i][j] = fmaf(aa[i], bb[j], acc[i][j]);
        }
    }

#pragma unroll
    for (int i = 0; i < 4; ++i) {
        const int m = m0 + (ty << 2) + i;
        const int n = n0 + (tx << 2);
        float v[4] = {acc[i][0], acc[i][1], acc[i][2], acc[i][3]};
        const size_t co = (size_t)m * ldc + n;
        if constexpr (EPI == EP_BF16) {
            *(bf4*)((bf16*)Cv + co) = pack4(v[0], v[1], v[2], v[3]);
        } else if constexpr (EPI == EP_SOFTPLUS) {
            *(bf4*)((bf16*)Cv + co) = pack4(
                softplus_f(v[0] + bias[n + 0]), softplus_f(v[1] + bias[n + 1]),
                softplus_f(v[2] + bias[n + 2]), softplus_f(v[3] + bias[n + 3]));
        } else if constexpr (EPI == EP_GELU) {
            *(bf4*)((bf16*)Cv + co) = pack4(
                gelu_f(v[0] + bias[n + 0]), gelu_f(v[1] + bias[n + 1]),
                gelu_f(v[2] + bias[n + 2]), gelu_f(v[3] + bias[n + 3]));
        } else if constexpr (EPI == EP_F32) {
            float4 o = {v[0], v[1], v[2], v[3]};
            *(float4*)((float*)Cv + co) = o;
        } else if constexpr (EPI == EP_RESF) {
            float4 rv = *(const float4*)((const float*)resv + co);
            float4 o = {v[0] + rv.x, v[1] + rv.y, v[2] + rv.z, v[3] + rv.w};
            *(float4*)((float*)Cv + co) = o;
        } else if constexpr (EPI == EP_ACC) {
            float* cp = (float*)Cv + co;
            float4 old = *(const float4*)cp;
            float4 o = {v[0] + old.x, v[1] + old.y, v[2] + old.z, v[3] + old.w};
            *(float4*)cp = o;
        } else if constexpr (EPI == EP_BIASRES) {
            float4 rv = ld4((const bf16*)resv + co);
            float4 o = {v[0] + bias[n + 0] + rv.x, v[1] + bias[n + 1] + rv.y,
                        v[2] + bias[n + 2] + rv.z, v[3] + bias[n + 3] + rv.w};
            *(float4*)((float*)Cv + co) = o;
        }
    }
}

// ---------------- depthwise conv (D_CONV=2) + SiLU ----------------
__global__ __launch_bounds__(256) void conv_silu_kernel(
    const bf16* __restrict__ xz, const float* __restrict__ cw,
    const float* __restrict__ cb, bf16* __restrict__ xic, int nbr)
{
    const int idx = blockIdx.x * 256 + threadIdx.x;
    const int c4 = (idx & 255) << 2;
    const int row = idx >> 8;
    const int l = row & (LL - 1);
    const int lnbr = l + nbr;
    const bool valid = (lnbr >= 0) && (lnbr < LL);

    const bf16* pc = xz + (size_t)row * (2 * DI) + c4;
    float4 cur = ld4(pc);
    float4 prv = make_float4(0.f, 0.f, 0.f, 0.f);
    if (valid) prv = ld4(pc + (ptrdiff_t)nbr * (2 * DI));

    float w0[4], w1[4];
#pragma unroll
    for (int q = 0; q < 4; ++q) { w0[q] = cw[(c4 + q) * 2]; w1[q] = cw[(c4 + q) * 2 + 1]; }
    float4 bb = ld4(cb + c4);

    *(bf4*)(xic + (size_t)row * DI + c4) = pack4(
        silu_f(fmaf(w0[0], prv.x, fmaf(w1[0], cur.x, bb.x))),
        silu_f(fmaf(w0[1], prv.y, fmaf(w1[1], cur.y, bb.y))),
        silu_f(fmaf(w0[2], prv.z, fmaf(w1[2], cur.z, bb.z))),
        silu_f(fmaf(w0[3], prv.w, fmaf(w1[3], cur.w, bb.w))));
}

// ---------------- chunked selective scan ----------------
// Phase 1: per (b,d,chunk) — local scan from h=0; store H_local (final h) and
// P = exp(a_s * sum_dt) (chunk decay). Layout P/H: [((b*NCH+c)*DS+s)*DI + d].
__global__ __launch_bounds__(256) void scan_p1(
    const bf16* __restrict__ xic, const bf16* __restrict__ dtb,
    const float* __restrict__ xdb, const float* __restrict__ A_log,
    float* __restrict__ P, float* __restrict__ H, int t0, int tstep)
{
    const int g = blockIdx.x * 256 + threadIdx.x;
    const int d = g & (DI - 1);
    const int rest = g >> 10;
    const int chunk = rest & (NCH - 1);
    const int b = rest >> 6;

    float a[DS], h[DS];
#pragma unroll
    for (int s = 0; s < DS; ++s) { a[s] = -__expf(A_log[d * DS + s]); h[s] = 0.f; }

    __shared__ float sB[CH][DS];
    for (int i = threadIdx.x; i < CH * DS; i += 256) {
        const int it = i >> 4, s = i & 15;
        const int t = t0 + (chunk * CH + it) * tstep;
        sB[it][s] = xdb[((size_t)(b * LL + t)) * 64 + DTR + s];
    }
    __syncthreads();

    float sumdt = 0.f;
    for (int it = 0; it < CH; ++it) {
        const int t = t0 + (chunk * CH + it) * tstep;
        const size_t row = (size_t)(b * LL + t);
        const float dtv = b2f(dtb[row * DI + d]);
        const float u = b2f(xic[row * DI + d]);
        sumdt += dtv;
        const float du = dtv * u;
#pragma unroll
        for (int s = 0; s < DS; ++s)
            h[s] = fmaf(__expf(dtv * a[s]), h[s], du * sB[it][s]);
    }
    const size_t base = ((size_t)((b * NCH + chunk) * DS)) * DI + d;
#pragma unroll
    for (int s = 0; s < DS; ++s) {
        P[base + (size_t)s * DI] = __expf(a[s] * sumdt);
        H[base + (size_t)s * DI] = h[s];
    }
}

// Phase 2: per (b,s,d) — compose chunk states sequentially; rewrite H[c] in
// place with the state ENTERING chunk c.
__global__ __launch_bounds__(256) void scan_p2(
    const float* __restrict__ P, float* __restrict__ H)
{
    const int g = blockIdx.x * 256 + threadIdx.x;   // 131072 threads
    const int d = g & (DI - 1);
    const int rest = g >> 10;
    const int s = rest & 15;
    const int b = rest >> 4;
    float h = 0.f;
    for (int c = 0; c < NCH; ++c) {
        const size_t idx = ((size_t)((b * NCH + c) * DS + s)) * DI + d;
        const float Pv = P[idx];
        const float Hv = H[idx];
        H[idx] = h;
        h = fmaf(Pv, h, Hv);
    }
}

// Phase 3: per (b,d,chunk) — replay chunk from true h_init; fuse D-skip and
// silu(z) gate; write y in place over dt (bf16, coalesced across d).
__global__ __launch_bounds__(256) void scan_p3(
    const bf16* __restrict__ xic, const bf16* __restrict__ xz,
    const float* __restrict__ xdb, bf16* __restrict__ dty,
    const float* __restrict__ A_log, const float* __restrict__ Dskip,
    const float* __restrict__ H, int t0, int tstep)
{
    const int g = blockIdx.x * 256 + threadIdx.x;
    const int d = g & (DI - 1);
    const int rest = g >> 10;
    const int chunk = rest & (NCH - 1);
    const int b = rest >> 6;

    float a[DS], h[DS];
    const size_t base = ((size_t)((b * NCH + chunk) * DS)) * DI + d;
#pragma unroll
    for (int s = 0; s < DS; ++s) {
        a[s] = -__expf(A_log[d * DS + s]);
        h[s] = H[base + (size_t)s * DI];
    }
    const float dsk = Dskip[d];

    __shared__ float sBC[CH][2 * DS];
    for (int i = threadIdx.x; i < CH * 2 * DS; i += 256) {
        const int it = i >> 5, j = i & 31;
        const int t = t0 + (chunk * CH + it) * tstep;
        sBC[it][j] = xdb[((size_t)(b * LL + t)) * 64 + DTR + j];
    }
    __syncthreads();

    for (int it = 0; it < CH; ++it) {
        const int t = t0 + (chunk * CH + it) * tstep;
        const size_t row = (size_t)(b * LL + t);
        const float dtv = b2f(dty[row * DI + d]);
        const float u = b2f(xic[row * DI + d]);
        const float zv = b2f(xz[row * (2 * DI) + DI + d]);
        const float du = dtv * u;
        float y = 0.f;
#pragma unroll
        for (int s = 0; s < DS; ++s) {
            h[s] = fmaf(__expf(dtv * a[s]), h[s], du * sBC[it][s]);
            y = fmaf(h[s], sBC[it][DS + s], y);
        }
        y = fmaf(u, dsk, y);
        dty[row * DI + d] = __float2bfloat16(y * silu_f(zv));
    }
}

// ---------------- layernorm (fp32 in; OUT: 0=bf16 ws, 1=fp32 d_out) ----------------
template <int OUTF>
__global__ __launch_bounds__(256) void ln_kernel(
    const float* __restrict__ in, const float* __restrict__ g,
    const float* __restrict__ bta, void* __restrict__ outv)
{
    const int row = blockIdx.x;
    const int t = threadIdx.x;
    const float* p = in + (size_t)row * DM;
    const float v0 = p[t];
    const float v1 = p[t + 256];
    float sm = v0 + v1;
    float sq = v0 * v0 + v1 * v1;
#pragma unroll
    for (int off = 32; off > 0; off >>= 1) {
        sm += __shfl_xor(sm, off);
        sq += __shfl_xor(sq, off);
    }
    __shared__ float red[8];
    const int w = t >> 6;
    if ((t & 63) == 0) { red[w] = sm; red[4 + w] = sq; }
    __syncthreads();
    sm = red[0] + red[1] + red[2] + red[3];
    sq = red[4] + red[5] + red[6] + red[7];
    const float mean = sm * (1.f / DM);
    const float var = sq * (1.f / DM) - mean * mean;
    const float rstd = rsqrtf(var + 1e-5f);
    const float o0 = (v0 - mean) * rstd * g[t] + bta[t];
    const float o1 = (v1 - mean) * rstd * g[t + 256] + bta[t + 256];
    if constexpr (OUTF == 0) {
        bf16* out = (bf16*)outv;
        out[(size_t)row * DM + t] = __float2bfloat16(o0);
        out[(size_t)row * DM + t + 256] = __float2bfloat16(o1);
    } else {
        float* out = (float*)outv;
        out[(size_t)row * DM + t] = o0;
        out[(size_t)row * DM + t + 256] = o1;
    }
}

// ---------------------------------------------------------------------------
extern "C" void kernel_launch(void* const* d_in, const int* in_sizes, int n_in,
                              void* d_out, int out_size, void* d_ws, size_t ws_size,
                              hipStream_t stream)
{
    const float* x = (const float*)d_in[0];
    const float* ffn_w1 = (const float*)d_in[19];
    const float* ffn_b1 = (const float*)d_in[20];
    const float* ffn_w2 = (const float*)d_in[21];
    const float* ffn_b2 = (const float*)d_in[22];
    const float* ln1_g = (const float*)d_in[23];
    const float* ln1_b = (const float*)d_in[24];
    const float* ln2_g = (const float*)d_in[25];
    const float* ln2_b = (const float*)d_in[26];

    char* p = (char*)d_ws;
    auto alloc = [&](size_t bytes) { void* r = (void*)p; p += (bytes + 255) & ~(size_t)255; return r; };
    bf16* xz   = (bf16*)alloc((size_t)BL * 2048 * 2);   // xz / FFN hidden (reused)
    bf16* xic  = (bf16*)alloc((size_t)BL * DI * 2);     // conv output u
    bf16* dtb  = (bf16*)alloc((size_t)BL * DI * 2);     // dt -> y (in place)
    float* xdb = (float*)alloc((size_t)BL * 64 * 4);    // x_dbl (fp32)
    float* sum = (float*)alloc((size_t)BL * DM * 4);    // residual accumulator (fp32)
    bf16* x1   = (bf16*)alloc((size_t)BL * DM * 2);     // LN1 output
    float* Pc  = (float*)alloc((size_t)BB * NCH * DS * DI * 4);  // chunk decay
    float* Hc  = (float*)alloc((size_t)BB * NCH * DS * DI * 4);  // chunk state

    const dim3 blk(256);
    for (int dir = 0; dir < 2; ++dir) {
        const int o = 1 + dir * 9;
        const float* in_proj = (const float*)d_in[o + 0];
        const float* conv_w  = (const float*)d_in[o + 1];
        const float* conv_b  = (const float*)d_in[o + 2];
        const float* x_proj  = (const float*)d_in[o + 3];
        const float* dt_w    = (const float*)d_in[o + 4];
        const float* dt_b    = (const float*)d_in[o + 5];
        const float* A_log   = (const float*)d_in[o + 6];
        const float* Dskip   = (const float*)d_in[o + 7];
        const float* out_proj= (const float*)d_in[o + 8];

        const int nbr = (dir == 0) ? -1 : +1;
        const int t0 = (dir == 0) ? 0 : (LL - 1);
        const int tstep = (dir == 0) ? 1 : -1;

        gemm_nt<EP_BF16, float><<<dim3((2 * DI) / 64, BL / 64), blk, 0, stream>>>(
            x, DM, in_proj, DM, xz, 2 * DI, DM, nullptr, nullptr);
        conv_silu_kernel<<<BL, blk, 0, stream>>>(xz, conv_w, conv_b, xic, nbr);
        gemm_nt<EP_F32, bf16><<<dim3(1, BL / 64), blk, 0, stream>>>(
            xic, DI, x_proj, DI, xdb, 64, DI, nullptr, nullptr);
        gemm_nt<EP_SOFTPLUS, float><<<dim3(DI / 64, BL / 64), blk, 0, stream>>>(
            xdb, 64, dt_w, DTR, dtb, DI, DTR, dt_b, nullptr);

        // chunked scan: local scans -> compose chunk states -> replay w/ gate
        scan_p1<<<(BB * NCH * DI) / 256, blk, 0, stream>>>(
            xic, dtb, xdb, A_log, Pc, Hc, t0, tstep);
        scan_p2<<<(BB * DS * DI) / 256, blk, 0, stream>>>(Pc, Hc);
        scan_p3<<<(BB * NCH * DI) / 256, blk, 0, stream>>>(
            xic, xz, xdb, dtb, A_log, Dskip, Hc, t0, tstep);

        if (dir == 0)
            gemm_nt<EP_RESF, bf16><<<dim3(DM / 64, BL / 64), blk, 0, stream>>>(
                dtb, DI, out_proj, DI, sum, DM, DI, nullptr, x);
        else
            gemm_nt<EP_ACC, bf16><<<dim3(DM / 64, BL / 64), blk, 0, stream>>>(
                dtb, DI, out_proj, DI, sum, DM, DI, nullptr, nullptr);
    }

    // LN1 -> x1 (bf16)
    ln_kernel<0><<<BL, blk, 0, stream>>>(sum, ln1_g, ln1_b, x1);
    // h = gelu(x1 @ w1^T + b1) -> xz (bf16)
    gemm_nt<EP_GELU, bf16><<<dim3(DFF / 64, BL / 64), blk, 0, stream>>>(
        x1, DM, ffn_w1, DM, xz, DFF, DM, ffn_b1, nullptr);
    // sum = h @ w2^T + b2 + x1 (fp32)
    gemm_nt<EP_BIASRES, bf16><<<dim3(DM / 64, BL / 64), blk, 0, stream>>>(
        xz, DFF, ffn_w2, DFF, sum, DM, DFF, ffn_b2, x1);
    // LN2 -> fp32 output
    ln_kernel<1><<<BL, blk, 0, stream>>>(sum, ln2_g, ln2_b, d_out);
}

// Round 8
// 1530.582 us; speedup vs baseline: 3.8378x; 1.9826x over previous
//
#include <hip/hip_runtime.h>
#include <hip/hip_bf16.h>

#define BB 8
#define LL 2048
#define DM 512
#define DI 1024
#define DS 16
#define DTR 32
#define DFF 2048
#define BL (BB * LL)
#define CH 32
#define NCH (LL / CH)   // 64

typedef __hip_bfloat16 bf16;
struct bf4 { bf16 x, y, z, w; };
typedef __attribute__((ext_vector_type(8))) short short8;
typedef __attribute__((ext_vector_type(4))) float floatx4;

__device__ __forceinline__ float silu_f(float x) { return x / (1.f + __expf(-x)); }
__device__ __forceinline__ float softplus_f(float x) { return x > 20.f ? x : log1pf(__expf(x)); }
__device__ __forceinline__ float gelu_f(float x) { return 0.5f * x * (1.f + erff(x * 0.70710678118654752f)); }
__device__ __forceinline__ float b2f(bf16 v) { return __bfloat162float(v); }

__device__ __forceinline__ float4 ld4(const float* p) { return *(const float4*)p; }
__device__ __forceinline__ float4 ld4(const bf16* p) {
    bf4 v = *(const bf4*)p;
    return make_float4(b2f(v.x), b2f(v.y), b2f(v.z), b2f(v.w));
}
__device__ __forceinline__ bf4 pack4(float a, float b, float c, float d) {
    bf4 o; o.x = __float2bfloat16(a); o.y = __float2bfloat16(b);
    o.z = __float2bfloat16(c); o.w = __float2bfloat16(d); return o;
}

enum { EP_BF16, EP_SOFTPLUS, EP_GELU, EP_F32, EP_RESF, EP_ACC, EP_BIASRES };

// ---------------- fp32 -> bf16 conversion ----------------
__global__ __launch_bounds__(256) void cvt_kernel(const float* __restrict__ in,
                                                  bf16* __restrict__ out, int n4)
{
    int i = blockIdx.x * 256 + threadIdx.x;
    if (i < n4) {
        float4 v = *(const float4*)(in + (size_t)i * 4);
        *(bf4*)(out + (size_t)i * 4) = pack4(v.x, v.y, v.z, v.w);
    }
}

// ---------------- MFMA bf16 NT GEMM: C[m,n] = sum_k A[m,k]*W[n,k] ----------------
// 128xBN tile, BK=32, 256 threads (4 waves, 2x2 wave grid), 16x16x32 MFMA.
template <int EPI, int BN>
__global__ __launch_bounds__(256) void gemm_mfma(
    const bf16* __restrict__ A, int lda,
    const bf16* __restrict__ W, int ldb,
    void* __restrict__ Cv, int ldc, int K,
    const float* __restrict__ bias, const void* __restrict__ resv)
{
    constexpr int BM = 128, BK = 32, LDP = 40;     // LDS pitch: 40 bf16 (2-way only)
    constexpr int NA = (BM * BK / 8) / 256;        // A 16B-chunks per thread (2)
    constexpr int NW = (BN * BK / 8) / 256;        // W chunks per thread (2 or 1)
    constexpr int NT = BN / 32;                    // n-tiles per wave (4 or 2)
    __shared__ bf16 sA[BM * LDP];
    __shared__ bf16 sW[BN * LDP];

    const int tid = threadIdx.x;
    const int wave = tid >> 6, lane = tid & 63;
    const int col = lane & 15, quad = lane >> 4;
    const int m0 = blockIdx.y * BM, n0 = blockIdx.x * BN;
    const int wm = (wave >> 1) * 64, wn = (wave & 1) * (BN / 2);

    floatx4 acc[4][NT] = {};

    for (int k0 = 0; k0 < K; k0 += BK) {
        float4 av[NA], wv[NW];
#pragma unroll
        for (int q = 0; q < NA; ++q) {
            const int c = tid + q * 256;
            const int r = c >> 2, kc = (c & 3) << 3;
            av[q] = *(const float4*)(A + (size_t)(m0 + r) * lda + k0 + kc);
        }
#pragma unroll
        for (int q = 0; q < NW; ++q) {
            const int c = tid + q * 256;
            const int r = c >> 2, kc = (c & 3) << 3;
            wv[q] = *(const float4*)(W + (size_t)(n0 + r) * ldb + k0 + kc);
        }
        __syncthreads();
#pragma unroll
        for (int q = 0; q < NA; ++q) {
            const int c = tid + q * 256;
            const int r = c >> 2, kc = (c & 3) << 3;
            *(float4*)(sA + r * LDP + kc) = av[q];
        }
#pragma unroll
        for (int q = 0; q < NW; ++q) {
            const int c = tid + q * 256;
            const int r = c >> 2, kc = (c & 3) << 3;
            *(float4*)(sW + r * LDP + kc) = wv[q];
        }
        __syncthreads();

        short8 af[4], wf[NT];
#pragma unroll
        for (int i = 0; i < 4; ++i)
            af[i] = *(const short8*)(sA + (wm + i * 16 + col) * LDP + quad * 8);
#pragma unroll
        for (int j = 0; j < NT; ++j)
            wf[j] = *(const short8*)(sW + (wn + j * 16 + col) * LDP + quad * 8);
#pragma unroll
        for (int i = 0; i < 4; ++i)
#pragma unroll
            for (int j = 0; j < NT; ++j)
                acc[i][j] = __builtin_amdgcn_mfma_f32_16x16x32_bf16(
                    af[i], wf[j], acc[i][j], 0, 0, 0);
    }

#pragma unroll
    for (int i = 0; i < 4; ++i) {
#pragma unroll
        for (int j = 0; j < NT; ++j) {
            const int n = n0 + wn + j * 16 + col;
#pragma unroll
            for (int r = 0; r < 4; ++r) {
                const int m = m0 + wm + i * 16 + quad * 4 + r;
                const float v = acc[i][j][r];
                const size_t co = (size_t)m * ldc + n;
                if constexpr (EPI == EP_BF16) {
                    ((bf16*)Cv)[co] = __float2bfloat16(v);
                } else if constexpr (EPI == EP_GELU) {
                    ((bf16*)Cv)[co] = __float2bfloat16(gelu_f(v + bias[n]));
                } else if constexpr (EPI == EP_F32) {
                    ((float*)Cv)[co] = v;
                } else if constexpr (EPI == EP_RESF) {
                    ((float*)Cv)[co] = v + ((const float*)resv)[co];
                } else if constexpr (EPI == EP_ACC) {
                    ((float*)Cv)[co] += v;
                } else if constexpr (EPI == EP_BIASRES) {
                    ((float*)Cv)[co] = v + bias[n] + b2f(((const bf16*)resv)[co]);
                }
            }
        }
    }
}

// ---------------- VALU NT GEMM (kept for dt: K=32) ----------------
template <int EPI, typename TA>
__global__ __launch_bounds__(256) void gemm_nt(
    const TA* __restrict__ A, int lda,
    const float* __restrict__ W, int ldb,
    void* __restrict__ Cv, int ldc,
    int K,
    const float* __restrict__ bias,
    const void* __restrict__ resv)
{
    __shared__ float As[16][64];
    __shared__ float Bs[16][64];
    const int tid = threadIdx.x;
    const int tx = tid & 15, ty = tid >> 4;
    const int m0 = blockIdx.y * 64, n0 = blockIdx.x * 64;
    const int lrow = tid >> 2;
    const int lcol = (tid & 3) << 2;

    const TA* Ap = A + (size_t)(m0 + lrow) * lda + lcol;
    const float* Bp = W + (size_t)(n0 + lrow) * ldb + lcol;

    float acc[4][4] = {};

    for (int k0 = 0; k0 < K; k0 += 16) {
        float4 av = ld4(Ap + k0);
        float4 bv = ld4(Bp + k0);
        __syncthreads();
        As[lcol + 0][lrow] = av.x; As[lcol + 1][lrow] = av.y;
        As[lcol + 2][lrow] = av.z; As[lcol + 3][lrow] = av.w;
        Bs[lcol + 0][lrow] = bv.x; Bs[lcol + 1][lrow] = bv.y;
        Bs[lcol + 2][lrow] = bv.z; Bs[lcol + 3][lrow] = bv.w;
        __syncthreads();
#pragma unroll
        for (int kk = 0; kk < 16; ++kk) {
            float4 a4 = *(const float4*)(&As[kk][ty << 2]);
            float4 b4 = *(const float4*)(&Bs[kk][tx << 2]);
            float aa[4] = {a4.x, a4.y, a4.z, a4.w};
            float bb[4] = {b4.x, b4.y, b4.z, b4.w};
#pragma unroll
            for (int i = 0; i < 4; ++i)
#pragma unroll
                for (int j = 0; j < 4; ++j)
                    acc[i][j] = fmaf(aa[i], bb[j], acc[i][j]);
        }
    }

#pragma unroll
    for (int i = 0; i < 4; ++i) {
        const int m = m0 + (ty << 2) + i;
        const int n = n0 + (tx << 2);
        float v[4] = {acc[i][0], acc[i][1], acc[i][2], acc[i][3]};
        const size_t co = (size_t)m * ldc + n;
        if constexpr (EPI == EP_SOFTPLUS) {
            *(bf4*)((bf16*)Cv + co) = pack4(
                softplus_f(v[0] + bias[n + 0]), softplus_f(v[1] + bias[n + 1]),
                softplus_f(v[2] + bias[n + 2]), softplus_f(v[3] + bias[n + 3]));
        } else if constexpr (EPI == EP_F32) {
            float4 o = {v[0], v[1], v[2], v[3]};
            *(float4*)((float*)Cv + co) = o;
        }
    }
}

// ---------------- depthwise conv (D_CONV=2) + SiLU ----------------
__global__ __launch_bounds__(256) void conv_silu_kernel(
    const bf16* __restrict__ xz, const float* __restrict__ cw,
    const float* __restrict__ cb, bf16* __restrict__ xic, int nbr)
{
    const int idx = blockIdx.x * 256 + threadIdx.x;
    const int c4 = (idx & 255) << 2;
    const int row = idx >> 8;
    const int l = row & (LL - 1);
    const int lnbr = l + nbr;
    const bool valid = (lnbr >= 0) && (lnbr < LL);

    const bf16* pc = xz + (size_t)row * (2 * DI) + c4;
    float4 cur = ld4(pc);
    float4 prv = make_float4(0.f, 0.f, 0.f, 0.f);
    if (valid) prv = ld4(pc + (ptrdiff_t)nbr * (2 * DI));

    float w0[4], w1[4];
#pragma unroll
    for (int q = 0; q < 4; ++q) { w0[q] = cw[(c4 + q) * 2]; w1[q] = cw[(c4 + q) * 2 + 1]; }
    float4 bb = ld4(cb + c4);

    *(bf4*)(xic + (size_t)row * DI + c4) = pack4(
        silu_f(fmaf(w0[0], prv.x, fmaf(w1[0], cur.x, bb.x))),
        silu_f(fmaf(w0[1], prv.y, fmaf(w1[1], cur.y, bb.y))),
        silu_f(fmaf(w0[2], prv.z, fmaf(w1[2], cur.z, bb.z))),
        silu_f(fmaf(w0[3], prv.w, fmaf(w1[3], cur.w, bb.w))));
}

// ---------------- chunked selective scan ----------------
// P1: per (b,d,chunk) — local scan from h=0; store H_local and sum_dt.
__global__ __launch_bounds__(256) void scan_p1(
    const bf16* __restrict__ xic, const bf16* __restrict__ dtb,
    const float* __restrict__ xdb, const float* __restrict__ A_log,
    float* __restrict__ SD, float* __restrict__ H, int t0, int tstep)
{
    const int g = blockIdx.x * 256 + threadIdx.x;
    const int d = g & (DI - 1);
    const int rest = g >> 10;
    const int chunk = rest & (NCH - 1);
    const int b = rest >> 6;

    float a[DS], h[DS];
#pragma unroll
    for (int s = 0; s < DS; ++s) { a[s] = -__expf(A_log[d * DS + s]); h[s] = 0.f; }

    __shared__ float sB[CH][DS];
    for (int i = threadIdx.x; i < CH * DS; i += 256) {
        const int it = i >> 4, s = i & 15;
        const int t = t0 + (chunk * CH + it) * tstep;
        sB[it][s] = xdb[((size_t)(b * LL + t)) * 64 + DTR + s];
    }
    __syncthreads();

    float sumdt = 0.f;
    for (int it = 0; it < CH; ++it) {
        const int t = t0 + (chunk * CH + it) * tstep;
        const size_t row = (size_t)(b * LL + t);
        const float dtv = b2f(dtb[row * DI + d]);
        const float u = b2f(xic[row * DI + d]);
        sumdt += dtv;
        const float du = dtv * u;
#pragma unroll
        for (int s = 0; s < DS; ++s)
            h[s] = fmaf(__expf(dtv * a[s]), h[s], du * sB[it][s]);
    }
    SD[((size_t)(b * NCH + chunk)) * DI + d] = sumdt;
    const size_t base = ((size_t)((b * NCH + chunk) * DS)) * DI + d;
#pragma unroll
    for (int s = 0; s < DS; ++s)
        H[base + (size_t)s * DI] = h[s];
}

// P2: per (b,s,d) — compose chunk states; rewrite H[c] with entering state.
__global__ __launch_bounds__(256) void scan_p2(
    const float* __restrict__ SD, float* __restrict__ H,
    const float* __restrict__ A_log)
{
    const int g = blockIdx.x * 256 + threadIdx.x;   // 131072 threads
    const int d = g & (DI - 1);
    const int rest = g >> 10;
    const int s = rest & 15;
    const int b = rest >> 4;
    const float a = -__expf(A_log[d * DS + s]);
    float h = 0.f;
    for (int c = 0; c < NCH; ++c) {
        const float sd = SD[((size_t)(b * NCH + c)) * DI + d];
        const size_t idx = ((size_t)((b * NCH + c) * DS + s)) * DI + d;
        const float Pv = __expf(a * sd);
        const float Hv = H[idx];
        H[idx] = h;
        h = fmaf(Pv, h, Hv);
    }
}

// P3: per (b,d,chunk) — replay from true h_init; fuse D-skip + silu(z) gate.
__global__ __launch_bounds__(256) void scan_p3(
    const bf16* __restrict__ xic, const bf16* __restrict__ xz,
    const float* __restrict__ xdb, bf16* __restrict__ dty,
    const float* __restrict__ A_log, const float* __restrict__ Dskip,
    const float* __restrict__ H, int t0, int tstep)
{
    const int g = blockIdx.x * 256 + threadIdx.x;
    const int d = g & (DI - 1);
    const int rest = g >> 10;
    const int chunk = rest & (NCH - 1);
    const int b = rest >> 6;

    float a[DS], h[DS];
    const size_t base = ((size_t)((b * NCH + chunk) * DS)) * DI + d;
#pragma unroll
    for (int s = 0; s < DS; ++s) {
        a[s] = -__expf(A_log[d * DS + s]);
        h[s] = H[base + (size_t)s * DI];
    }
    const float dsk = Dskip[d];

    __shared__ float sBC[CH][2 * DS];
    for (int i = threadIdx.x; i < CH * 2 * DS; i += 256) {
        const int it = i >> 5, j = i & 31;
        const int t = t0 + (chunk * CH + it) * tstep;
        sBC[it][j] = xdb[((size_t)(b * LL + t)) * 64 + DTR + j];
    }
    __syncthreads();

    for (int it = 0; it < CH; ++it) {
        const int t = t0 + (chunk * CH + it) * tstep;
        const size_t row = (size_t)(b * LL + t);
        const float dtv = b2f(dty[row * DI + d]);
        const float u = b2f(xic[row * DI + d]);
        const float zv = b2f(xz[row * (2 * DI) + DI + d]);
        const float du = dtv * u;
        float y = 0.f;
#pragma unroll
        for (int s = 0; s < DS; ++s) {
            h[s] = fmaf(__expf(dtv * a[s]), h[s], du * sBC[it][s]);
            y = fmaf(h[s], sBC[it][DS + s], y);
        }
        y = fmaf(u, dsk, y);
        dty[row * DI + d] = __float2bfloat16(y * silu_f(zv));
    }
}

// ---------------- layernorm (fp32 in; OUT: 0=bf16 ws, 1=fp32 d_out) ----------------
template <int OUTF>
__global__ __launch_bounds__(256) void ln_kernel(
    const float* __restrict__ in, const float* __restrict__ g,
    const float* __restrict__ bta, void* __restrict__ outv)
{
    const int row = blockIdx.x;
    const int t = threadIdx.x;
    const float* p = in + (size_t)row * DM;
    const float v0 = p[t];
    const float v1 = p[t + 256];
    float sm = v0 + v1;
    float sq = v0 * v0 + v1 * v1;
#pragma unroll
    for (int off = 32; off > 0; off >>= 1) {
        sm += __shfl_xor(sm, off);
        sq += __shfl_xor(sq, off);
    }
    __shared__ float red[8];
    const int w = t >> 6;
    if ((t & 63) == 0) { red[w] = sm; red[4 + w] = sq; }
    __syncthreads();
    sm = red[0] + red[1] + red[2] + red[3];
    sq = red[4] + red[5] + red[6] + red[7];
    const float mean = sm * (1.f / DM);
    const float var = sq * (1.f / DM) - mean * mean;
    const float rstd = rsqrtf(var + 1e-5f);
    const float o0 = (v0 - mean) * rstd * g[t] + bta[t];
    const float o1 = (v1 - mean) * rstd * g[t + 256] + bta[t + 256];
    if constexpr (OUTF == 0) {
        bf16* out = (bf16*)outv;
        out[(size_t)row * DM + t] = __float2bfloat16(o0);
        out[(size_t)row * DM + t + 256] = __float2bfloat16(o1);
    } else {
        float* out = (float*)outv;
        out[(size_t)row * DM + t] = o0;
        out[(size_t)row * DM + t + 256] = o1;
    }
}

// ---------------------------------------------------------------------------
extern "C" void kernel_launch(void* const* d_in, const int* in_sizes, int n_in,
                              void* d_out, int out_size, void* d_ws, size_t ws_size,
                              hipStream_t stream)
{
    const float* x = (const float*)d_in[0];
    const float* ffn_w1 = (const float*)d_in[19];
    const float* ffn_b1 = (const float*)d_in[20];
    const float* ffn_w2 = (const float*)d_in[21];
    const float* ffn_b2 = (const float*)d_in[22];
    const float* ln1_g = (const float*)d_in[23];
    const float* ln1_b = (const float*)d_in[24];
    const float* ln2_g = (const float*)d_in[25];
    const float* ln2_b = (const float*)d_in[26];

    char* p = (char*)d_ws;
    auto alloc = [&](size_t bytes) { void* r = (void*)p; p += (bytes + 255) & ~(size_t)255; return r; };
    bf16* xz   = (bf16*)alloc((size_t)BL * 2048 * 2);   // xz / FFN hidden (reused)
    bf16* xic  = (bf16*)alloc((size_t)BL * DI * 2);     // conv output u
    bf16* dtb  = (bf16*)alloc((size_t)BL * DI * 2);     // dt -> y (in place)
    float* xdb = (float*)alloc((size_t)BL * 64 * 4);    // x_dbl (fp32)
    float* sum = (float*)alloc((size_t)BL * DM * 4);    // residual accumulator (fp32)
    bf16* x1   = (bf16*)alloc((size_t)BL * DM * 2);     // LN1 output
    bf16* xb   = (bf16*)alloc((size_t)BL * DM * 2);     // x in bf16
    float* SD  = (float*)alloc((size_t)BB * NCH * DI * 4);        // chunk sum_dt
    float* Hc  = (float*)alloc((size_t)BB * NCH * DS * DI * 4);   // chunk states
    bf16* wip[2], *wxp[2], *wop[2];
    for (int d = 0; d < 2; ++d) {
        wip[d] = (bf16*)alloc((size_t)2 * DI * DM * 2);
        wxp[d] = (bf16*)alloc((size_t)64 * DI * 2);
        wop[d] = (bf16*)alloc((size_t)DM * DI * 2);
    }
    bf16* w1b = (bf16*)alloc((size_t)DFF * DM * 2);
    bf16* w2b = (bf16*)alloc((size_t)DM * DFF * 2);

    auto cvt = [&](const float* src, bf16* dst, size_t n) {
        int n4 = (int)(n / 4);
        cvt_kernel<<<(n4 + 255) / 256, 256, 0, stream>>>(src, dst, n4);
    };
    cvt(x, xb, (size_t)BL * DM);
    for (int d = 0; d < 2; ++d) {
        const int o = 1 + d * 9;
        cvt((const float*)d_in[o + 0], wip[d], (size_t)2 * DI * DM);
        cvt((const float*)d_in[o + 3], wxp[d], (size_t)64 * DI);
        cvt((const float*)d_in[o + 8], wop[d], (size_t)DM * DI);
    }
    cvt(ffn_w1, w1b, (size_t)DFF * DM);
    cvt(ffn_w2, w2b, (size_t)DM * DFF);

    const dim3 blk(256);
    for (int dir = 0; dir < 2; ++dir) {
        const int o = 1 + dir * 9;
        const float* conv_w = (const float*)d_in[o + 1];
        const float* conv_b = (const float*)d_in[o + 2];
        const float* dt_w   = (const float*)d_in[o + 4];
        const float* dt_b   = (const float*)d_in[o + 5];
        const float* A_log  = (const float*)d_in[o + 6];
        const float* Dskip  = (const float*)d_in[o + 7];

        const int nbr = (dir == 0) ? -1 : +1;
        const int t0 = (dir == 0) ? 0 : (LL - 1);
        const int tstep = (dir == 0) ? 1 : -1;

        // xz = x @ in_proj^T : (BL, 2048) bf16  [MFMA]
        gemm_mfma<EP_BF16, 128><<<dim3((2 * DI) / 128, BL / 128), blk, 0, stream>>>(
            xb, DM, wip[dir], DM, xz, 2 * DI, DM, nullptr, nullptr);
        // depthwise conv + silu -> xic
        conv_silu_kernel<<<BL, blk, 0, stream>>>(xz, conv_w, conv_b, xic, nbr);
        // x_dbl = xic @ x_proj^T : (BL, 64) fp32  [MFMA, BN=64]
        gemm_mfma<EP_F32, 64><<<dim3(1, BL / 128), blk, 0, stream>>>(
            xic, DI, wxp[dir], DI, xdb, 64, DI, nullptr, nullptr);
        // dt = softplus(x_dbl[:, :32] @ dt_w^T + dt_b) : (BL, 1024) bf16  [VALU, K=32]
        gemm_nt<EP_SOFTPLUS, float><<<dim3(DI / 64, BL / 64), blk, 0, stream>>>(
            xdb, 64, dt_w, DTR, dtb, DI, DTR, dt_b, nullptr);

        // chunked scan
        scan_p1<<<(BB * NCH * DI) / 256, blk, 0, stream>>>(
            xic, dtb, xdb, A_log, SD, Hc, t0, tstep);
        scan_p2<<<(BB * DS * DI) / 256, blk, 0, stream>>>(SD, Hc, A_log);
        scan_p3<<<(BB * NCH * DI) / 256, blk, 0, stream>>>(
            xic, xz, xdb, dtb, A_log, Dskip, Hc, t0, tstep);

        // sum = x + y@out_proj^T (dir0) / += (dir1)  [MFMA]
        if (dir == 0)
            gemm_mfma<EP_RESF, 128><<<dim3(DM / 128, BL / 128), blk, 0, stream>>>(
                dtb, DI, wop[dir], DI, sum, DM, DI, nullptr, x);
        else
            gemm_mfma<EP_ACC, 128><<<dim3(DM / 128, BL / 128), blk, 0, stream>>>(
                dtb, DI, wop[dir], DI, sum, DM, DI, nullptr, nullptr);
    }

    // LN1 -> x1 (bf16)
    ln_kernel<0><<<BL, blk, 0, stream>>>(sum, ln1_g, ln1_b, x1);
    // h = gelu(x1 @ w1^T + b1) -> xz (bf16)  [MFMA]
    gemm_mfma<EP_GELU, 128><<<dim3(DFF / 128, BL / 128), blk, 0, stream>>>(
        x1, DM, w1b, DM, xz, DFF, DM, ffn_b1, nullptr);
    // sum = h @ w2^T + b2 + x1 (fp32)  [MFMA]
    gemm_mfma<EP_BIASRES, 128><<<dim3(DM / 128, BL / 128), blk, 0, stream>>>(
        xz, DFF, w2b, DFF, sum, DM, DFF, ffn_b2, x1);
    // LN2 -> fp32 output
    ln_kernel<1><<<BL, blk, 0, stream>>>(sum, ln2_g, ln2_b, d_out);
}